// Round 10
// baseline (184.111 us; speedup 1.0000x reference)
//
#include <hip/hip_runtime.h>

typedef _Float16 f16;
typedef _Float16 f16x4 __attribute__((ext_vector_type(4)));
typedef _Float16 f16x8 __attribute__((ext_vector_type(8)));
typedef float f32x4 __attribute__((ext_vector_type(4)));

// async global->LDS, 16B per lane; LDS dest = wave-uniform base + lane*16
#define LOADLDS16(gp, lp)                                                     \
  __builtin_amdgcn_global_load_lds(                                           \
      (const __attribute__((address_space(1))) void*)(gp),                    \
      (__attribute__((address_space(3))) void*)(lp), 16, 0, 0)

// ---------------------------------------------------------------------------
// Elementwise cast f32 -> f16 (both activations in one launch)
// ---------------------------------------------------------------------------
__global__ __launch_bounds__(256) void k_cast2(const float* __restrict__ a,
                                               const float* __restrict__ b,
                                               f16* __restrict__ ya,
                                               f16* __restrict__ yb) {
  int i = blockIdx.x * 256 + threadIdx.x;
  const float* x;
  f16* y;
  if (i < 1048576) {
    x = a; y = ya;
  } else {
    x = b; y = yb; i -= 1048576;
  }
  float4 v = reinterpret_cast<const float4*>(x)[i];
  f16x4 o;
  o[0] = (f16)v.x; o[1] = (f16)v.y; o[2] = (f16)v.z; o[3] = (f16)v.w;
  reinterpret_cast<f16x4*>(y)[i] = o;
}

// ---------------------------------------------------------------------------
// Cast + transpose weights: W[1024][1024] f32 -> Wt[N][K] f16  (Wt[n][k]=W[k][n])
// ---------------------------------------------------------------------------
__global__ __launch_bounds__(256) void k_castw_t(
    const float* __restrict__ w0, const float* __restrict__ w1,
    const float* __restrict__ w2, const float* __restrict__ w3,
    f16* __restrict__ o0, f16* __restrict__ o1, f16* __restrict__ o2,
    f16* __restrict__ o3) {
  const float* W;
  f16* O;
  switch (blockIdx.z) {
    case 0: W = w0; O = o0; break;
    case 1: W = w1; O = o1; break;
    case 2: W = w2; O = o2; break;
    default: W = w3; O = o3; break;
  }
  __shared__ f16 T[64][72];
  const int tid = threadIdx.x;
  const int r0 = blockIdx.y * 64, c0 = blockIdx.x * 64;
#pragma unroll
  for (int i = 0; i < 4; ++i) {
    int c = i * 256 + tid;
    int row = c >> 4, col = (c & 15) * 4;
    float4 v = *reinterpret_cast<const float4*>(W + (size_t)(r0 + row) * 1024 + c0 + col);
    T[col + 0][row] = (f16)v.x;
    T[col + 1][row] = (f16)v.y;
    T[col + 2][row] = (f16)v.z;
    T[col + 3][row] = (f16)v.w;
  }
  __syncthreads();
#pragma unroll
  for (int i = 0; i < 2; ++i) {
    int c = i * 256 + tid;
    int cc = c >> 3, ro = (c & 7) * 8;
    f16x8 v;
#pragma unroll
    for (int j = 0; j < 8; ++j) v[j] = T[cc][ro + j];
    *reinterpret_cast<f16x8*>(O + (size_t)(c0 + cc) * 1024 + r0 + ro) = v;
  }
}

// ---------------------------------------------------------------------------
// Fused QKV projection: C[4096, 3072], cols 0-1023 = Xq@Wqt, 1024-2047 =
// Xkv@Wkt, 2048-3071 = Xkv@Wvt. m97 structure: BM=BN=128, BK=64, 4 waves.
// ---------------------------------------------------------------------------
__global__ __launch_bounds__(256) void k_gemm_qkv(const f16* __restrict__ Xq,
                                                  const f16* __restrict__ Xkv,
                                                  const f16* __restrict__ Bt,
                                                  f16* __restrict__ outp) {
  __shared__ f16 As[128 * 64];  // 16 KB
  __shared__ f16 Bs[128 * 64];  // 16 KB
  const int tid = threadIdx.x;
  const int w = tid >> 6, l = tid & 63;
  const int lr = l & 15, lq = l >> 4;
  const int m0 = blockIdx.y * 128, n0 = blockIdx.x * 128;
  const f16* A = (n0 < 1024) ? Xq : Xkv;
  const int wr = (w >> 1) * 64, wc = (w & 1) * 64;
  const int K = 1024;
  f32x4 acc[4][4] = {};
  for (int kt = 0; kt < K; kt += 64) {
#pragma unroll
    for (int i = 0; i < 4; ++i) {
      int c = (i * 4 + w) * 64 + l;
      LOADLDS16(A + (size_t)(m0 + (c >> 3)) * K + kt + (c & 7) * 8,
                As + (size_t)(i * 4 + w) * 512);
      LOADLDS16(Bt + (size_t)(n0 + (c >> 3)) * K + kt + (c & 7) * 8,
                Bs + (size_t)(i * 4 + w) * 512);
    }
    __syncthreads();
#pragma unroll
    for (int kk = 0; kk < 2; ++kk) {
      f16x8 af[4], bf[4];
#pragma unroll
      for (int m = 0; m < 4; ++m)
        af[m] = *reinterpret_cast<const f16x8*>(As + (wr + m * 16 + lr) * 64 + kk * 32 + lq * 8);
#pragma unroll
      for (int n = 0; n < 4; ++n)
        bf[n] = *reinterpret_cast<const f16x8*>(Bs + (wc + n * 16 + lr) * 64 + kk * 32 + lq * 8);
#pragma unroll
      for (int m = 0; m < 4; ++m)
#pragma unroll
        for (int n = 0; n < 4; ++n)
          acc[m][n] = __builtin_amdgcn_mfma_f32_16x16x32_f16(af[m], bf[n], acc[m][n], 0, 0, 0);
    }
    __syncthreads();
  }
#pragma unroll
  for (int m = 0; m < 4; ++m)
#pragma unroll
    for (int n = 0; n < 4; ++n)
#pragma unroll
      for (int r = 0; r < 4; ++r) {
        int row = m0 + wr + m * 16 + lq * 4 + r;
        int col = n0 + wc + n * 16 + lr;
        int b = row >> 10, s = row & 1023;
        int plane = col >> 10, cc = col & 1023;
        int h = cc >> 6, dh = cc & 63;
        outp[(size_t)plane * 4194304 +
             (((size_t)(b * 16 + h)) * 1024 + s) * 64 + dh] = (f16)acc[m][n][r];
      }
}

// ---------------------------------------------------------------------------
// Output GEMM: C[M,N] f32 = A[M,K] @ Bt[N,K]^T. BM=64, BN=128 (512 blocks).
// ---------------------------------------------------------------------------
__global__ __launch_bounds__(256) void k_gemm_o(const f16* __restrict__ A,
                                                const f16* __restrict__ Bt,
                                                float* __restrict__ out, int M,
                                                int N, int K) {
  __shared__ f16 As[64 * 64];
  __shared__ f16 Bs[128 * 64];
  const int tid = threadIdx.x;
  const int w = tid >> 6, l = tid & 63;
  const int lr = l & 15, lq = l >> 4;
  const int m0 = blockIdx.y * 64, n0 = blockIdx.x * 128;
  const int wr = (w >> 1) * 32, wc = (w & 1) * 64;
  f32x4 acc[2][4] = {};
  for (int kt = 0; kt < K; kt += 64) {
#pragma unroll
    for (int i = 0; i < 2; ++i) {
      int c = (i * 4 + w) * 64 + l;
      LOADLDS16(A + (size_t)(m0 + (c >> 3)) * K + kt + (c & 7) * 8,
                As + (size_t)(i * 4 + w) * 512);
    }
#pragma unroll
    for (int i = 0; i < 4; ++i) {
      int c = (i * 4 + w) * 64 + l;
      LOADLDS16(Bt + (size_t)(n0 + (c >> 3)) * K + kt + (c & 7) * 8,
                Bs + (size_t)(i * 4 + w) * 512);
    }
    __syncthreads();
#pragma unroll
    for (int kk = 0; kk < 2; ++kk) {
      f16x8 af[2], bf[4];
#pragma unroll
      for (int m = 0; m < 2; ++m)
        af[m] = *reinterpret_cast<const f16x8*>(As + (wr + m * 16 + lr) * 64 + kk * 32 + lq * 8);
#pragma unroll
      for (int n = 0; n < 4; ++n)
        bf[n] = *reinterpret_cast<const f16x8*>(Bs + (wc + n * 16 + lr) * 64 + kk * 32 + lq * 8);
#pragma unroll
      for (int m = 0; m < 2; ++m)
#pragma unroll
        for (int n = 0; n < 4; ++n)
          acc[m][n] = __builtin_amdgcn_mfma_f32_16x16x32_f16(af[m], bf[n], acc[m][n], 0, 0, 0);
    }
    __syncthreads();
  }
#pragma unroll
  for (int m = 0; m < 2; ++m)
#pragma unroll
    for (int n = 0; n < 4; ++n)
#pragma unroll
      for (int r = 0; r < 4; ++r) {
        int row = m0 + wr + m * 16 + lq * 4 + r;
        int col = n0 + wc + n * 16 + lr;
        out[(size_t)row * N + col] = acc[m][n][r];
      }
}

// ---------------------------------------------------------------------------
// V transpose per head: vb[bh][1024][64] -> vtb[bh][64][1024]
// ---------------------------------------------------------------------------
__global__ __launch_bounds__(256) void k_vtrans(const f16* __restrict__ vb,
                                                f16* __restrict__ vtb) {
  const int bh = blockIdx.y, s0 = blockIdx.x * 64;
  __shared__ f16 T[64][72];
  const int tid = threadIdx.x;
  const f16* src = vb + (size_t)bh * 1024 * 64;
#pragma unroll
  for (int i = 0; i < 2; ++i) {
    int c = i * 256 + tid;
    int row = c >> 3, co = (c & 7) * 8;
    f16x8 v = *reinterpret_cast<const f16x8*>(src + (size_t)(s0 + row) * 64 + co);
#pragma unroll
    for (int j = 0; j < 8; ++j) T[co + j][row] = v[j];
  }
  __syncthreads();
  f16* dst = vtb + (size_t)bh * 64 * 1024;
#pragma unroll
  for (int i = 0; i < 2; ++i) {
    int c = i * 256 + tid;
    int dh = c >> 3, so = (c & 7) * 8;
    f16x8 v;
#pragma unroll
    for (int j = 0; j < 8; ++j) v[j] = T[dh][so + j];
    *reinterpret_cast<f16x8*>(dst + (size_t)dh * 1024 + s0 + so) = v;
  }
}

// ---------------------------------------------------------------------------
// Fused flash attention (T5: scores = QK^T + bias, no 1/sqrt scale).
// v10: NO staging, NO barriers (m169 lesson: K/V is L2-resident at this size;
// LDS-staging it is pure overhead, and barrier-lockstep was the 3x-null wall
// of rounds 7-9). Each wave reads K / V^T / bias fragments DIRECTLY from
// global per-lane in MFMA layout; all 12 loads issued at the top of the body
// (one latency-exposure window, partial vmcnt waits per use). Waves fully
// independent -> TLP hides L2/L3 latency. Only LDS left: wave-private Ps.
// Swapped QK^T + defer-max + deferred rsum (verified rounds 6-9) unchanged.
// ---------------------------------------------------------------------------
__global__ __launch_bounds__(256) void k_attn(const f16* __restrict__ qb,
                                              const f16* __restrict__ kb,
                                              const f16* __restrict__ vtb,
                                              const float* __restrict__ bias,
                                              f16* __restrict__ ctx) {
  const int bid = blockIdx.x;
  const int ord = (bid & 7) * 64 + (bid >> 3);  // XCD-chunked: 2 heads/XCD
  const int h = ord >> 5, qt = (ord >> 2) & 7, b = ord & 3;
  const int bh = b * 16 + h;
  const int q0 = qt * 128;
  const int tid = threadIdx.x, w = tid >> 6, l = tid & 63;
  const int lr = l & 15, lq = l >> 4;

  __shared__ f16 Ps[4][1280];  // per-wave [q=32][kv pad 40]

  // Q fragments: frag A rows w*32+lr, frag B rows w*32+16+lr
  const f16* qp = qb + ((size_t)bh * 1024 + q0 + w * 32 + lr) * 64 + lq * 8;
  f16x8 qA0 = *reinterpret_cast<const f16x8*>(qp);
  f16x8 qA1 = *reinterpret_cast<const f16x8*>(qp + 32);
  f16x8 qB0 = *reinterpret_cast<const f16x8*>(qp + 1024);
  f16x8 qB1 = *reinterpret_cast<const f16x8*>(qp + 1056);

  f32x4 OA[4] = {}, OB[4] = {};
  float mA = -3.0e38f, mB = -3.0e38f, rsA = 0.f, rsB = 0.f;  // q-row = lr

  // per-lane fragment bases
  const f16* kp0 = kb + (size_t)bh * 65536 + (size_t)lr * 64 + lq * 8;
  const f16* vp0 = vtb + (size_t)bh * 65536 + (size_t)lr * 1024 + lq * 8;
  const float* bq0 =
      bias + ((size_t)h * 1024 + q0 + w * 32 + lr) * 1024 + lq * 4;
  const float* bq1 = bq0 + 16 * 1024;

#pragma unroll 1
  for (int t = 0; t < 32; ++t) {
    // ---- issue ALL per-lane loads for this tile up front ----
    // K: row kv = t*32 + c*16 + lr, dh = lq*8 (+32)
    f16x8 kf[2][2];
#pragma unroll
    for (int c = 0; c < 2; ++c) {
      const f16* kp = kp0 + (size_t)(t * 32 + c * 16) * 64;
      kf[c][0] = *reinterpret_cast<const f16x8*>(kp);
      kf[c][1] = *reinterpret_cast<const f16x8*>(kp + 32);
    }
    // bias: f32x4 at [q-row][kv = t*32 + c*16 + lq*4]
    f32x4 bf[2][2];
#pragma unroll
    for (int c = 0; c < 2; ++c) {
      bf[0][c] = *reinterpret_cast<const f32x4*>(bq0 + t * 32 + c * 16);
      bf[1][c] = *reinterpret_cast<const f32x4*>(bq1 + t * 32 + c * 16);
    }
    // V^T: row dh = c*16 + lr, kv = t*32 + lq*8
    f16x8 vf[4];
#pragma unroll
    for (int c = 0; c < 4; ++c)
      vf[c] = *reinterpret_cast<const f16x8*>(vp0 + (size_t)c * 16 * 1024 + t * 32);

    // ---- S^T = K Q^T (zero-init) ----
    f32x4 S[2][2] = {};
    __builtin_amdgcn_s_setprio(1);
#pragma unroll
    for (int c = 0; c < 2; ++c) {
      S[0][c] = __builtin_amdgcn_mfma_f32_16x16x32_f16(kf[c][0], qA0, S[0][c], 0, 0, 0);
      S[0][c] = __builtin_amdgcn_mfma_f32_16x16x32_f16(kf[c][1], qA1, S[0][c], 0, 0, 0);
      S[1][c] = __builtin_amdgcn_mfma_f32_16x16x32_f16(kf[c][0], qB0, S[1][c], 0, 0, 0);
      S[1][c] = __builtin_amdgcn_mfma_f32_16x16x32_f16(kf[c][1], qB1, S[1][c], 0, 0, 0);
    }
    __builtin_amdgcn_s_setprio(0);

    // ---- + bias ----
#pragma unroll
    for (int f = 0; f < 2; ++f)
#pragma unroll
      for (int c = 0; c < 2; ++c)
#pragma unroll
        for (int r = 0; r < 4; ++r) S[f][c][r] += bf[f][c][r];

    // ---- defer-max (T13): per-lane bound check, rare reduce+rescale ----
    float tA = fmaxf(fmaxf(fmaxf(S[0][0][0], S[0][0][1]), fmaxf(S[0][0][2], S[0][0][3])),
                     fmaxf(fmaxf(S[0][1][0], S[0][1][1]), fmaxf(S[0][1][2], S[0][1][3])));
    float tB = fmaxf(fmaxf(fmaxf(S[1][0][0], S[1][0][1]), fmaxf(S[1][0][2], S[1][0][3])),
                     fmaxf(fmaxf(S[1][1][0], S[1][1][1]), fmaxf(S[1][1][2], S[1][1][3])));
    bool ok = (tA <= mA + 8.0f) && (tB <= mB + 8.0f);
    if (!__all(ok)) {
      tA = fmaxf(tA, __shfl_xor(tA, 16, 64));
      tA = fmaxf(tA, __shfl_xor(tA, 32, 64));
      tB = fmaxf(tB, __shfl_xor(tB, 16, 64));
      tB = fmaxf(tB, __shfl_xor(tB, 32, 64));
      float mnA = fmaxf(mA, tA), mnB = fmaxf(mB, tB);
      float scA = __expf(mA - mnA), scB = __expf(mB - mnB);
      mA = mnA; mB = mnB;
      rsA *= scA; rsB *= scB;
      int sb = l & 48;
#pragma unroll
      for (int r = 0; r < 4; ++r) {
        float sA = __shfl(scA, sb | (lq * 4 + r), 64);
        float sB = __shfl(scB, sb | (lq * 4 + r), 64);
#pragma unroll
        for (int c = 0; c < 4; ++c) {
          OA[c][r] *= sA;
          OB[c][r] *= sB;
        }
      }
    }

    // ---- P = exp(S - m); per-lane rsum; vectorized b64 spill ----
#pragma unroll
    for (int c = 0; c < 2; ++c) {
      f32x4 pA, pB;
#pragma unroll
      for (int r = 0; r < 4; ++r) {
        pA[r] = __expf(S[0][c][r] - mA);
        pB[r] = __expf(S[1][c][r] - mB);
      }
      rsA += (pA[0] + pA[1]) + (pA[2] + pA[3]);
      rsB += (pB[0] + pB[1]) + (pB[2] + pB[3]);
      f16x4 hA = {(f16)pA[0], (f16)pA[1], (f16)pA[2], (f16)pA[3]};
      f16x4 hB = {(f16)pB[0], (f16)pB[1], (f16)pB[2], (f16)pB[3]};
      *reinterpret_cast<f16x4*>(&Ps[w][lr * 40 + c * 16 + lq * 4]) = hA;
      *reinterpret_cast<f16x4*>(&Ps[w][(16 + lr) * 40 + c * 16 + lq * 4]) = hB;
    }

    // ---- O += P @ V (wave-private Ps; lgkmcnt orders round-trip) ----
    {
      f16x8 paA = *reinterpret_cast<const f16x8*>(&Ps[w][lr * 40 + lq * 8]);
      f16x8 paB = *reinterpret_cast<const f16x8*>(&Ps[w][(16 + lr) * 40 + lq * 8]);
      __builtin_amdgcn_s_setprio(1);
#pragma unroll
      for (int c = 0; c < 4; ++c) {
        OA[c] = __builtin_amdgcn_mfma_f32_16x16x32_f16(paA, vf[c], OA[c], 0, 0, 0);
        OB[c] = __builtin_amdgcn_mfma_f32_16x16x32_f16(paB, vf[c], OB[c], 0, 0, 0);
      }
      __builtin_amdgcn_s_setprio(0);
    }
  }

  // ---- deferred sum reduction across the 4 lq replicas ----
  rsA += __shfl_xor(rsA, 16, 64);
  rsA += __shfl_xor(rsA, 32, 64);
  rsB += __shfl_xor(rsB, 16, 64);
  rsB += __shfl_xor(rsB, 32, 64);
  int sb = l & 48;

  // ---- epilogue: ctx[b][q][h*64+dh] f16 (O rows q=lq*4+r, cols dh=c*16+lr) ----
#pragma unroll
  for (int r = 0; r < 4; ++r) {
    float dA = __shfl(rsA, sb | (lq * 4 + r), 64);
    float dB = __shfl(rsB, sb | (lq * 4 + r), 64);
    int rowA = q0 + w * 32 + lq * 4 + r;
#pragma unroll
    for (int c = 0; c < 4; ++c) {
      int col = h * 64 + c * 16 + lr;
      ctx[((size_t)b * 1024 + rowA) * 1024 + col] = (f16)(OA[c][r] / dA);
      ctx[((size_t)b * 1024 + rowA + 16) * 1024 + col] = (f16)(OB[c][r] / dB);
    }
  }
}

// ---------------------------------------------------------------------------
extern "C" void kernel_launch(void* const* d_in, const int* in_sizes, int n_in,
                              void* d_out, int out_size, void* d_ws,
                              size_t ws_size, hipStream_t stream) {
  const float* input_ids = (const float*)d_in[0];
  const float* enc = (const float*)d_in[1];
  const float* bias = (const float*)d_in[2];
  const float* Wq = (const float*)d_in[3];
  const float* Wk = (const float*)d_in[4];
  const float* Wv = (const float*)d_in[5];
  const float* Wo = (const float*)d_in[6];

  char* ws = (char*)d_ws;
  const size_t MB = 1024 * 1024;
  f16* Xq  = (f16*)(ws + 0 * MB);   // 8 MB; dead after QKV-proj -> reused as ctx
  f16* Xkv = (f16*)(ws + 8 * MB);   // 8 MB; dead after QKV-proj -> reused as vtb
  f16* Wqt = (f16*)(ws + 16 * MB);  // 2 MB each; Wqt|Wkt|Wvt contiguous = [3072][1024]
  f16* Wkt = (f16*)(ws + 18 * MB);
  f16* Wvt = (f16*)(ws + 20 * MB);
  f16* Wot = (f16*)(ws + 22 * MB);
  f16* qbuf = (f16*)(ws + 24 * MB); // 8 MB [bh][s][dh]; kbuf/vbuf planes follow
  f16* kbuf = (f16*)(ws + 32 * MB);
  f16* vbuf = (f16*)(ws + 40 * MB);
  f16* vtb = Xkv;   // [bh][dh][sk]
  f16* ctxb = Xq;   // [4096][1024]

  k_cast2<<<8192, 256, 0, stream>>>(input_ids, enc, Xq, Xkv);
  k_castw_t<<<dim3(16, 16, 4), 256, 0, stream>>>(Wq, Wk, Wv, Wo, Wqt, Wkt, Wvt, Wot);

  // fused Q+K+V projection: N=3072 over [Wqt|Wkt|Wvt], per-block A select
  k_gemm_qkv<<<dim3(24, 32), 256, 0, stream>>>(Xq, Xkv, Wqt, qbuf);

  k_vtrans<<<dim3(16, 64), 256, 0, stream>>>(vbuf, vtb);

  k_attn<<<512, 256, 0, stream>>>(qbuf, kbuf, vtb, bias, ctxb);

  k_gemm_o<<<dim3(8, 64), 256, 0, stream>>>(ctxb, Wot, (float*)d_out, 4096, 1024, 1024);
}

// Round 11
// 141.287 us; speedup vs baseline: 1.3031x; 1.3031x over previous
//
#include <hip/hip_runtime.h>

typedef _Float16 f16;
typedef _Float16 f16x4 __attribute__((ext_vector_type(4)));
typedef _Float16 f16x8 __attribute__((ext_vector_type(8)));
typedef float f32x4 __attribute__((ext_vector_type(4)));

// async global->LDS, 16B per lane; LDS dest = wave-uniform base + lane*16
#define LOADLDS16(gp, lp)                                                     \
  __builtin_amdgcn_global_load_lds(                                           \
      (const __attribute__((address_space(1))) void*)(gp),                    \
      (__attribute__((address_space(3))) void*)(lp), 16, 0, 0)

// ---------------------------------------------------------------------------
// Elementwise cast f32 -> f16 (both activations in one launch)
// ---------------------------------------------------------------------------
__global__ __launch_bounds__(256) void k_cast2(const float* __restrict__ a,
                                               const float* __restrict__ b,
                                               f16* __restrict__ ya,
                                               f16* __restrict__ yb) {
  int i = blockIdx.x * 256 + threadIdx.x;
  const float* x;
  f16* y;
  if (i < 1048576) {
    x = a; y = ya;
  } else {
    x = b; y = yb; i -= 1048576;
  }
  float4 v = reinterpret_cast<const float4*>(x)[i];
  f16x4 o;
  o[0] = (f16)v.x; o[1] = (f16)v.y; o[2] = (f16)v.z; o[3] = (f16)v.w;
  reinterpret_cast<f16x4*>(y)[i] = o;
}

// ---------------------------------------------------------------------------
// Cast + transpose weights: W[1024][1024] f32 -> Wt[N][K] f16  (Wt[n][k]=W[k][n])
// ---------------------------------------------------------------------------
__global__ __launch_bounds__(256) void k_castw_t(
    const float* __restrict__ w0, const float* __restrict__ w1,
    const float* __restrict__ w2, const float* __restrict__ w3,
    f16* __restrict__ o0, f16* __restrict__ o1, f16* __restrict__ o2,
    f16* __restrict__ o3) {
  const float* W;
  f16* O;
  switch (blockIdx.z) {
    case 0: W = w0; O = o0; break;
    case 1: W = w1; O = o1; break;
    case 2: W = w2; O = o2; break;
    default: W = w3; O = o3; break;
  }
  __shared__ f16 T[64][72];
  const int tid = threadIdx.x;
  const int r0 = blockIdx.y * 64, c0 = blockIdx.x * 64;
#pragma unroll
  for (int i = 0; i < 4; ++i) {
    int c = i * 256 + tid;
    int row = c >> 4, col = (c & 15) * 4;
    float4 v = *reinterpret_cast<const float4*>(W + (size_t)(r0 + row) * 1024 + c0 + col);
    T[col + 0][row] = (f16)v.x;
    T[col + 1][row] = (f16)v.y;
    T[col + 2][row] = (f16)v.z;
    T[col + 3][row] = (f16)v.w;
  }
  __syncthreads();
#pragma unroll
  for (int i = 0; i < 2; ++i) {
    int c = i * 256 + tid;
    int cc = c >> 3, ro = (c & 7) * 8;
    f16x8 v;
#pragma unroll
    for (int j = 0; j < 8; ++j) v[j] = T[cc][ro + j];
    *reinterpret_cast<f16x8*>(O + (size_t)(c0 + cc) * 1024 + r0 + ro) = v;
  }
}

// ---------------------------------------------------------------------------
// Fused QKV projection: C[4096, 3072], cols 0-1023 = Xq@Wqt, 1024-2047 =
// Xkv@Wkt, 2048-3071 = Xkv@Wvt. m97 structure: BM=BN=128, BK=64, 4 waves.
// ---------------------------------------------------------------------------
__global__ __launch_bounds__(256) void k_gemm_qkv(const f16* __restrict__ Xq,
                                                  const f16* __restrict__ Xkv,
                                                  const f16* __restrict__ Bt,
                                                  f16* __restrict__ outp) {
  __shared__ f16 As[128 * 64];  // 16 KB
  __shared__ f16 Bs[128 * 64];  // 16 KB
  const int tid = threadIdx.x;
  const int w = tid >> 6, l = tid & 63;
  const int lr = l & 15, lq = l >> 4;
  const int m0 = blockIdx.y * 128, n0 = blockIdx.x * 128;
  const f16* A = (n0 < 1024) ? Xq : Xkv;
  const int wr = (w >> 1) * 64, wc = (w & 1) * 64;
  const int K = 1024;
  f32x4 acc[4][4] = {};
  for (int kt = 0; kt < K; kt += 64) {
#pragma unroll
    for (int i = 0; i < 4; ++i) {
      int c = (i * 4 + w) * 64 + l;
      LOADLDS16(A + (size_t)(m0 + (c >> 3)) * K + kt + (c & 7) * 8,
                As + (size_t)(i * 4 + w) * 512);
      LOADLDS16(Bt + (size_t)(n0 + (c >> 3)) * K + kt + (c & 7) * 8,
                Bs + (size_t)(i * 4 + w) * 512);
    }
    __syncthreads();
#pragma unroll
    for (int kk = 0; kk < 2; ++kk) {
      f16x8 af[4], bf[4];
#pragma unroll
      for (int m = 0; m < 4; ++m)
        af[m] = *reinterpret_cast<const f16x8*>(As + (wr + m * 16 + lr) * 64 + kk * 32 + lq * 8);
#pragma unroll
      for (int n = 0; n < 4; ++n)
        bf[n] = *reinterpret_cast<const f16x8*>(Bs + (wc + n * 16 + lr) * 64 + kk * 32 + lq * 8);
#pragma unroll
      for (int m = 0; m < 4; ++m)
#pragma unroll
        for (int n = 0; n < 4; ++n)
          acc[m][n] = __builtin_amdgcn_mfma_f32_16x16x32_f16(af[m], bf[n], acc[m][n], 0, 0, 0);
    }
    __syncthreads();
  }
#pragma unroll
  for (int m = 0; m < 4; ++m)
#pragma unroll
    for (int n = 0; n < 4; ++n)
#pragma unroll
      for (int r = 0; r < 4; ++r) {
        int row = m0 + wr + m * 16 + lq * 4 + r;
        int col = n0 + wc + n * 16 + lr;
        int b = row >> 10, s = row & 1023;
        int plane = col >> 10, cc = col & 1023;
        int h = cc >> 6, dh = cc & 63;
        outp[(size_t)plane * 4194304 +
             (((size_t)(b * 16 + h)) * 1024 + s) * 64 + dh] = (f16)acc[m][n][r];
      }
}

// ---------------------------------------------------------------------------
// Output GEMM: C[M,N] f32 = A[M,K] @ Bt[N,K]^T. BM=64, BN=128 (512 blocks).
// ---------------------------------------------------------------------------
__global__ __launch_bounds__(256) void k_gemm_o(const f16* __restrict__ A,
                                                const f16* __restrict__ Bt,
                                                float* __restrict__ out, int M,
                                                int N, int K) {
  __shared__ f16 As[64 * 64];
  __shared__ f16 Bs[128 * 64];
  const int tid = threadIdx.x;
  const int w = tid >> 6, l = tid & 63;
  const int lr = l & 15, lq = l >> 4;
  const int m0 = blockIdx.y * 64, n0 = blockIdx.x * 128;
  const int wr = (w >> 1) * 32, wc = (w & 1) * 64;
  f32x4 acc[2][4] = {};
  for (int kt = 0; kt < K; kt += 64) {
#pragma unroll
    for (int i = 0; i < 2; ++i) {
      int c = (i * 4 + w) * 64 + l;
      LOADLDS16(A + (size_t)(m0 + (c >> 3)) * K + kt + (c & 7) * 8,
                As + (size_t)(i * 4 + w) * 512);
    }
#pragma unroll
    for (int i = 0; i < 4; ++i) {
      int c = (i * 4 + w) * 64 + l;
      LOADLDS16(Bt + (size_t)(n0 + (c >> 3)) * K + kt + (c & 7) * 8,
                Bs + (size_t)(i * 4 + w) * 512);
    }
    __syncthreads();
#pragma unroll
    for (int kk = 0; kk < 2; ++kk) {
      f16x8 af[2], bf[4];
#pragma unroll
      for (int m = 0; m < 2; ++m)
        af[m] = *reinterpret_cast<const f16x8*>(As + (wr + m * 16 + lr) * 64 + kk * 32 + lq * 8);
#pragma unroll
      for (int n = 0; n < 4; ++n)
        bf[n] = *reinterpret_cast<const f16x8*>(Bs + (wc + n * 16 + lr) * 64 + kk * 32 + lq * 8);
#pragma unroll
      for (int m = 0; m < 2; ++m)
#pragma unroll
        for (int n = 0; n < 4; ++n)
          acc[m][n] = __builtin_amdgcn_mfma_f32_16x16x32_f16(af[m], bf[n], acc[m][n], 0, 0, 0);
    }
    __syncthreads();
  }
#pragma unroll
  for (int m = 0; m < 2; ++m)
#pragma unroll
    for (int n = 0; n < 4; ++n)
#pragma unroll
      for (int r = 0; r < 4; ++r) {
        int row = m0 + wr + m * 16 + lq * 4 + r;
        int col = n0 + wc + n * 16 + lr;
        out[(size_t)row * N + col] = acc[m][n][r];
      }
}

// ---------------------------------------------------------------------------
// V transpose per head: vb[bh][1024][64] -> vtb[bh][64][1024]
// ---------------------------------------------------------------------------
__global__ __launch_bounds__(256) void k_vtrans(const f16* __restrict__ vb,
                                                f16* __restrict__ vtb) {
  const int bh = blockIdx.y, s0 = blockIdx.x * 64;
  __shared__ f16 T[64][72];
  const int tid = threadIdx.x;
  const f16* src = vb + (size_t)bh * 1024 * 64;
#pragma unroll
  for (int i = 0; i < 2; ++i) {
    int c = i * 256 + tid;
    int row = c >> 3, co = (c & 7) * 8;
    f16x8 v = *reinterpret_cast<const f16x8*>(src + (size_t)(s0 + row) * 64 + co);
#pragma unroll
    for (int j = 0; j < 8; ++j) T[co + j][row] = v[j];
  }
  __syncthreads();
  f16* dst = vtb + (size_t)bh * 64 * 1024;
#pragma unroll
  for (int i = 0; i < 2; ++i) {
    int c = i * 256 + tid;
    int dh = c >> 3, so = (c & 7) * 8;
    f16x8 v;
#pragma unroll
    for (int j = 0; j < 8; ++j) v[j] = T[dh][so + j];
    *reinterpret_cast<f16x8*>(dst + (size_t)dh * 1024 + s0 + so) = v;
  }
}

// ---------------------------------------------------------------------------
// Fused flash attention (T5: scores = QK^T + bias, no 1/sqrt scale).
// v11 = v7 base with KVBLK=64 (16 barrier periods instead of 32; 2x ILP per
// period: 4 independent c-blocks in QK and PV) and bias moved OUT of LDS to
// per-lane global f32x4 loads in exact S layout (issued at body top, pinned
// by sched_barrier(0), covered by the 2x-longer body).
// K/V [64][64] tiles double-buffered via DMA, granule-swizzle g^(row&7) on
// both (2-way / BW-floor for all fragment reads). P spill reuses [16][40] Ps
// in two kv-halves (WAR ordered by lgkmcnt, overlaps phase-1 PV).
// LDS = 16+16+5 = 37 KB -> 4 blocks/CU at grid 1024 (h,qt,b XCD-chunked).
// ---------------------------------------------------------------------------
__global__ __launch_bounds__(256) void k_attn(const f16* __restrict__ qb,
                                              const f16* __restrict__ kb,
                                              const f16* __restrict__ vtb,
                                              const float* __restrict__ bias,
                                              f16* __restrict__ ctx) {
  const int bid = blockIdx.x;
  const int ord = (bid & 7) * 128 + (bid >> 3);  // XCD-chunked: 2 heads/XCD
  const int h = ord >> 6, qt = (ord >> 2) & 15, b = ord & 3;
  const int bh = b * 16 + h;
  const int q0 = qt * 64;
  const int tid = threadIdx.x, w = tid >> 6, l = tid & 63;
  const int lr = l & 15, lq = l >> 4;

  __shared__ f16 Kb[2][4096];  // [kv=64][dh=64], granule swz g^(row&7)
  __shared__ f16 Vb[2][4096];  // [dh=64][kv=64], granule swz g^(row&7)
  __shared__ f16 Ps[4][640];   // per-wave [q=16][kv pad 40], two-phase reuse

  // Q B-fragment: Q[q=w*16+lr][dh=lq*8 (+32)]
  const f16* qp = qb + ((size_t)bh * 1024 + q0 + w * 16 + lr) * 64 + lq * 8;
  f16x8 qf0 = *reinterpret_cast<const f16x8*>(qp);
  f16x8 qf1 = *reinterpret_cast<const f16x8*>(qp + 32);

  f32x4 O[4] = {};
  float mrun = -3.0e38f, rsum = 0.f;  // per-lane; q-row = lr

  const f16* kbase = kb + (size_t)bh * 65536;
  const f16* vbase = vtb + (size_t)bh * 65536;
  // per-lane bias base: S[c] init needs bias[q=q0+w*16+lr][t*64+c*16+lq*4..+3]
  const float* bq = bias + ((size_t)h * 1024 + q0 + w * 16 + lr) * 1024 + lq * 4;

  // DMA staging: 512 chunks of 16B per tile; round i, wave w, lane l.
  auto stage = [&](int t, int nxt) {
#pragma unroll
    for (int i = 0; i < 2; ++i) {
      int c = (i * 4 + w) * 64 + l;
      int row = c >> 3, g = (c & 7) ^ (row & 7);
      LOADLDS16(kbase + (size_t)(t * 64 + row) * 64 + g * 8,
                &Kb[nxt][(i * 4 + w) * 512]);
      LOADLDS16(vbase + (size_t)row * 1024 + t * 64 + g * 8,
                &Vb[nxt][(i * 4 + w) * 512]);
    }
  };

  // ---- prologue: stage tile 0 ----
  stage(0, 0);
  __syncthreads();

#pragma unroll 1
  for (int t = 0; t < 16; ++t) {
    const int cur = t & 1;
    // ---- issue next tile's DMA + this tile's bias loads (pinned) ----
    if (t < 15) stage(t + 1, cur ^ 1);
    f32x4 bf[4];
#pragma unroll
    for (int c = 0; c < 4; ++c)
      bf[c] = *reinterpret_cast<const f32x4*>(bq + t * 64 + c * 16);
    __builtin_amdgcn_sched_barrier(0);

    // ---- S^T = K Q^T  (rows kv = c*16+lq*4+r, cols q = w*16+lr) ----
    f32x4 S[4] = {};
    __builtin_amdgcn_s_setprio(1);
#pragma unroll
    for (int c = 0; c < 4; ++c) {
      int row = c * 16 + lr;
      const f16* kbp = &Kb[cur][row * 64];
      f16x8 kf0 = *reinterpret_cast<const f16x8*>(kbp + ((lq ^ (row & 7)) * 8));
      f16x8 kf1 = *reinterpret_cast<const f16x8*>(kbp + (((4 + lq) ^ (row & 7)) * 8));
      S[c] = __builtin_amdgcn_mfma_f32_16x16x32_f16(kf0, qf0, S[c], 0, 0, 0);
      S[c] = __builtin_amdgcn_mfma_f32_16x16x32_f16(kf1, qf1, S[c], 0, 0, 0);
    }
    __builtin_amdgcn_s_setprio(0);

    // ---- + bias (registers) ----
#pragma unroll
    for (int c = 0; c < 4; ++c)
#pragma unroll
      for (int r = 0; r < 4; ++r) S[c][r] += bf[c][r];

    // ---- defer-max (T13): per-lane bound check; rare reduce+rescale ----
    float tmax = fmaxf(
        fmaxf(fmaxf(fmaxf(S[0][0], S[0][1]), fmaxf(S[0][2], S[0][3])),
              fmaxf(fmaxf(S[1][0], S[1][1]), fmaxf(S[1][2], S[1][3]))),
        fmaxf(fmaxf(fmaxf(S[2][0], S[2][1]), fmaxf(S[2][2], S[2][3])),
              fmaxf(fmaxf(S[3][0], S[3][1]), fmaxf(S[3][2], S[3][3]))));
    if (!__all(tmax <= mrun + 8.0f)) {
      tmax = fmaxf(tmax, __shfl_xor(tmax, 16, 64));
      tmax = fmaxf(tmax, __shfl_xor(tmax, 32, 64));
      float mnew = fmaxf(mrun, tmax);
      float sc = __expf(mrun - mnew);
      mrun = mnew;
      rsum *= sc;
      int sb = l & 48;
#pragma unroll
      for (int r = 0; r < 4; ++r) {
        float scO = __shfl(sc, sb | (lq * 4 + r), 64);
#pragma unroll
        for (int c = 0; c < 4; ++c) O[c][r] *= scO;
      }
    }

    // ---- phase A: P(kv 0-31) = exp, spill, read pa0 ----
#pragma unroll
    for (int c = 0; c < 2; ++c) {
      f32x4 p;
#pragma unroll
      for (int r = 0; r < 4; ++r) p[r] = __expf(S[c][r] - mrun);
      rsum += (p[0] + p[1]) + (p[2] + p[3]);
      f16x4 ph = {(f16)p[0], (f16)p[1], (f16)p[2], (f16)p[3]};
      *reinterpret_cast<f16x4*>(&Ps[w][lr * 40 + c * 16 + lq * 4]) = ph;
    }
    f16x8 pa0 = *reinterpret_cast<const f16x8*>(&Ps[w][lr * 40 + lq * 8]);

    // ---- phase B: P(kv 32-63) = exp, spill (same region; WAR via lgkm) ----
#pragma unroll
    for (int c = 2; c < 4; ++c) {
      f32x4 p;
#pragma unroll
      for (int r = 0; r < 4; ++r) p[r] = __expf(S[c][r] - mrun);
      rsum += (p[0] + p[1]) + (p[2] + p[3]);
      f16x4 ph = {(f16)p[0], (f16)p[1], (f16)p[2], (f16)p[3]};
      *reinterpret_cast<f16x4*>(&Ps[w][lr * 40 + (c - 2) * 16 + lq * 4]) = ph;
    }
    f16x8 pa1 = *reinterpret_cast<const f16x8*>(&Ps[w][lr * 40 + lq * 8]);

    // ---- O += P @ V ----
    __builtin_amdgcn_s_setprio(1);
#pragma unroll
    for (int c = 0; c < 4; ++c) {
      int row = c * 16 + lr;
      const f16* vbp = &Vb[cur][row * 64];
      f16x8 vf0 = *reinterpret_cast<const f16x8*>(vbp + ((lq ^ (row & 7)) * 8));
      f16x8 vf1 = *reinterpret_cast<const f16x8*>(vbp + (((4 + lq) ^ (row & 7)) * 8));
      O[c] = __builtin_amdgcn_mfma_f32_16x16x32_f16(pa0, vf0, O[c], 0, 0, 0);
      O[c] = __builtin_amdgcn_mfma_f32_16x16x32_f16(pa1, vf1, O[c], 0, 0, 0);
    }
    __builtin_amdgcn_s_setprio(0);

    __syncthreads();
  }

  // ---- deferred sum reduction across the 4 lq replicas ----
  rsum += __shfl_xor(rsum, 16, 64);
  rsum += __shfl_xor(rsum, 32, 64);
  int sb = l & 48;
  float rs[4];
#pragma unroll
  for (int r = 0; r < 4; ++r) rs[r] = __shfl(rsum, sb | (lq * 4 + r), 64);

  // ---- epilogue: ctx[b][q][h*64+dh] f16 (O: q=lq*4+r, dh=c*16+lr) ----
#pragma unroll
  for (int c = 0; c < 4; ++c)
#pragma unroll
    for (int r = 0; r < 4; ++r) {
      float o = O[c][r] / rs[r];
      int row = q0 + w * 16 + lq * 4 + r;
      ctx[((size_t)b * 1024 + row) * 1024 + h * 64 + c * 16 + lr] = (f16)o;
    }
}

// ---------------------------------------------------------------------------
extern "C" void kernel_launch(void* const* d_in, const int* in_sizes, int n_in,
                              void* d_out, int out_size, void* d_ws,
                              size_t ws_size, hipStream_t stream) {
  const float* input_ids = (const float*)d_in[0];
  const float* enc = (const float*)d_in[1];
  const float* bias = (const float*)d_in[2];
  const float* Wq = (const float*)d_in[3];
  const float* Wk = (const float*)d_in[4];
  const float* Wv = (const float*)d_in[5];
  const float* Wo = (const float*)d_in[6];

  char* ws = (char*)d_ws;
  const size_t MB = 1024 * 1024;
  f16* Xq  = (f16*)(ws + 0 * MB);   // 8 MB; dead after QKV-proj -> reused as ctx
  f16* Xkv = (f16*)(ws + 8 * MB);   // 8 MB; dead after QKV-proj -> reused as vtb
  f16* Wqt = (f16*)(ws + 16 * MB);  // 2 MB each; Wqt|Wkt|Wvt contiguous = [3072][1024]
  f16* Wkt = (f16*)(ws + 18 * MB);
  f16* Wvt = (f16*)(ws + 20 * MB);
  f16* Wot = (f16*)(ws + 22 * MB);
  f16* qbuf = (f16*)(ws + 24 * MB); // 8 MB [bh][s][dh]; kbuf/vbuf planes follow
  f16* kbuf = (f16*)(ws + 32 * MB);
  f16* vbuf = (f16*)(ws + 40 * MB);
  f16* vtb = Xkv;   // [bh][dh][sk]
  f16* ctxb = Xq;   // [4096][1024]

  k_cast2<<<8192, 256, 0, stream>>>(input_ids, enc, Xq, Xkv);
  k_castw_t<<<dim3(16, 16, 4), 256, 0, stream>>>(Wq, Wk, Wv, Wo, Wqt, Wkt, Wvt, Wot);

  // fused Q+K+V projection: N=3072 over [Wqt|Wkt|Wvt], per-block A select
  k_gemm_qkv<<<dim3(24, 32), 256, 0, stream>>>(Xq, Xkv, Wqt, qbuf);

  k_vtrans<<<dim3(16, 64), 256, 0, stream>>>(vbuf, vtb);

  k_attn<<<1024, 256, 0, stream>>>(qbuf, kbuf, vtb, bias, ctxb);

  k_gemm_o<<<dim3(8, 64), 256, 0, stream>>>(ctxb, Wot, (float*)d_out, 4096, 1024, 1024);
}

// Round 12
// 137.756 us; speedup vs baseline: 1.3365x; 1.0256x over previous
//
#include <hip/hip_runtime.h>

typedef _Float16 f16;
typedef _Float16 f16x4 __attribute__((ext_vector_type(4)));
typedef _Float16 f16x8 __attribute__((ext_vector_type(8)));
typedef float f32x4 __attribute__((ext_vector_type(4)));

// async global->LDS, 16B per lane; LDS dest = wave-uniform base + lane*16
#define LOADLDS16(gp, lp)                                                     \
  __builtin_amdgcn_global_load_lds(                                           \
      (const __attribute__((address_space(1))) void*)(gp),                    \
      (__attribute__((address_space(3))) void*)(lp), 16, 0, 0)

// ---------------------------------------------------------------------------
// Elementwise cast f32 -> f16 (both activations in one launch)
// ---------------------------------------------------------------------------
__global__ __launch_bounds__(256) void k_cast2(const float* __restrict__ a,
                                               const float* __restrict__ b,
                                               f16* __restrict__ ya,
                                               f16* __restrict__ yb) {
  int i = blockIdx.x * 256 + threadIdx.x;
  const float* x;
  f16* y;
  if (i < 1048576) {
    x = a; y = ya;
  } else {
    x = b; y = yb; i -= 1048576;
  }
  float4 v = reinterpret_cast<const float4*>(x)[i];
  f16x4 o;
  o[0] = (f16)v.x; o[1] = (f16)v.y; o[2] = (f16)v.z; o[3] = (f16)v.w;
  reinterpret_cast<f16x4*>(y)[i] = o;
}

// ---------------------------------------------------------------------------
// Cast + transpose weights: W[1024][1024] f32 -> Wt[N][K] f16  (Wt[n][k]=W[k][n])
// ---------------------------------------------------------------------------
__global__ __launch_bounds__(256) void k_castw_t(
    const float* __restrict__ w0, const float* __restrict__ w1,
    const float* __restrict__ w2, const float* __restrict__ w3,
    f16* __restrict__ o0, f16* __restrict__ o1, f16* __restrict__ o2,
    f16* __restrict__ o3) {
  const float* W;
  f16* O;
  switch (blockIdx.z) {
    case 0: W = w0; O = o0; break;
    case 1: W = w1; O = o1; break;
    case 2: W = w2; O = o2; break;
    default: W = w3; O = o3; break;
  }
  __shared__ f16 T[64][72];
  const int tid = threadIdx.x;
  const int r0 = blockIdx.y * 64, c0 = blockIdx.x * 64;
#pragma unroll
  for (int i = 0; i < 4; ++i) {
    int c = i * 256 + tid;
    int row = c >> 4, col = (c & 15) * 4;
    float4 v = *reinterpret_cast<const float4*>(W + (size_t)(r0 + row) * 1024 + c0 + col);
    T[col + 0][row] = (f16)v.x;
    T[col + 1][row] = (f16)v.y;
    T[col + 2][row] = (f16)v.z;
    T[col + 3][row] = (f16)v.w;
  }
  __syncthreads();
#pragma unroll
  for (int i = 0; i < 2; ++i) {
    int c = i * 256 + tid;
    int cc = c >> 3, ro = (c & 7) * 8;
    f16x8 v;
#pragma unroll
    for (int j = 0; j < 8; ++j) v[j] = T[cc][ro + j];
    *reinterpret_cast<f16x8*>(O + (size_t)(c0 + cc) * 1024 + r0 + ro) = v;
  }
}

// ---------------------------------------------------------------------------
// Fused QKV projection: C[4096, 3072], cols 0-1023 = Xq@Wqt, 1024-2047 =
// Xkv@Wkt, 2048-3071 = Xkv@Wvt. m97 structure: BM=BN=128, BK=64, 4 waves.
// Epilogue: planes 0,1 -> head layout [bh][s][dh]; plane 2 (V) -> TRANSPOSED
// [bh][dh][s] (f16x4 stores over consecutive s) = fused k_vtrans.
// ---------------------------------------------------------------------------
__global__ __launch_bounds__(256) void k_gemm_qkv(const f16* __restrict__ Xq,
                                                  const f16* __restrict__ Xkv,
                                                  const f16* __restrict__ Bt,
                                                  f16* __restrict__ outp) {
  __shared__ f16 As[128 * 64];  // 16 KB
  __shared__ f16 Bs[128 * 64];  // 16 KB
  const int tid = threadIdx.x;
  const int w = tid >> 6, l = tid & 63;
  const int lr = l & 15, lq = l >> 4;
  const int m0 = blockIdx.y * 128, n0 = blockIdx.x * 128;
  const f16* A = (n0 < 1024) ? Xq : Xkv;
  const int wr = (w >> 1) * 64, wc = (w & 1) * 64;
  const int K = 1024;
  f32x4 acc[4][4] = {};
  for (int kt = 0; kt < K; kt += 64) {
#pragma unroll
    for (int i = 0; i < 4; ++i) {
      int c = (i * 4 + w) * 64 + l;
      LOADLDS16(A + (size_t)(m0 + (c >> 3)) * K + kt + (c & 7) * 8,
                As + (size_t)(i * 4 + w) * 512);
      LOADLDS16(Bt + (size_t)(n0 + (c >> 3)) * K + kt + (c & 7) * 8,
                Bs + (size_t)(i * 4 + w) * 512);
    }
    __syncthreads();
#pragma unroll
    for (int kk = 0; kk < 2; ++kk) {
      f16x8 af[4], bf[4];
#pragma unroll
      for (int m = 0; m < 4; ++m)
        af[m] = *reinterpret_cast<const f16x8*>(As + (wr + m * 16 + lr) * 64 + kk * 32 + lq * 8);
#pragma unroll
      for (int n = 0; n < 4; ++n)
        bf[n] = *reinterpret_cast<const f16x8*>(Bs + (wc + n * 16 + lr) * 64 + kk * 32 + lq * 8);
#pragma unroll
      for (int m = 0; m < 4; ++m)
#pragma unroll
        for (int n = 0; n < 4; ++n)
          acc[m][n] = __builtin_amdgcn_mfma_f32_16x16x32_f16(af[m], bf[n], acc[m][n], 0, 0, 0);
    }
    __syncthreads();
  }
  const bool vplane = (n0 >= 2048);  // plane is block-uniform (n0 % 1024 == 0 blocks of 128)
#pragma unroll
  for (int m = 0; m < 4; ++m)
#pragma unroll
    for (int n = 0; n < 4; ++n) {
      int col = n0 + wc + n * 16 + lr;
      int row0 = m0 + wr + m * 16 + lq * 4;
      int b = row0 >> 10, s0 = row0 & 1023;
      int plane = col >> 10, cc = col & 1023;
      int h = cc >> 6, dh = cc & 63;
      if (vplane) {
        // V transposed: vtb[bh][dh][s], 4 consecutive s = one f16x4 store
        f16x4 v4;
#pragma unroll
        for (int r = 0; r < 4; ++r) v4[r] = (f16)acc[m][n][r];
        *reinterpret_cast<f16x4*>(
            outp + (size_t)2 * 4194304 +
            ((size_t)(b * 16 + h)) * 65536 + (size_t)dh * 1024 + s0) = v4;
      } else {
#pragma unroll
        for (int r = 0; r < 4; ++r)
          outp[(size_t)plane * 4194304 +
               (((size_t)(b * 16 + h)) * 1024 + s0 + r) * 64 + dh] =
              (f16)acc[m][n][r];
      }
    }
}

// ---------------------------------------------------------------------------
// Output GEMM: C[M,N] f32 = A[M,K] @ Bt[N,K]^T. BM=64, BN=128 (512 blocks).
// ---------------------------------------------------------------------------
__global__ __launch_bounds__(256) void k_gemm_o(const f16* __restrict__ A,
                                                const f16* __restrict__ Bt,
                                                float* __restrict__ out, int M,
                                                int N, int K) {
  __shared__ f16 As[64 * 64];
  __shared__ f16 Bs[128 * 64];
  const int tid = threadIdx.x;
  const int w = tid >> 6, l = tid & 63;
  const int lr = l & 15, lq = l >> 4;
  const int m0 = blockIdx.y * 64, n0 = blockIdx.x * 128;
  const int wr = (w >> 1) * 32, wc = (w & 1) * 64;
  f32x4 acc[2][4] = {};
  for (int kt = 0; kt < K; kt += 64) {
#pragma unroll
    for (int i = 0; i < 2; ++i) {
      int c = (i * 4 + w) * 64 + l;
      LOADLDS16(A + (size_t)(m0 + (c >> 3)) * K + kt + (c & 7) * 8,
                As + (size_t)(i * 4 + w) * 512);
    }
#pragma unroll
    for (int i = 0; i < 4; ++i) {
      int c = (i * 4 + w) * 64 + l;
      LOADLDS16(Bt + (size_t)(n0 + (c >> 3)) * K + kt + (c & 7) * 8,
                Bs + (size_t)(i * 4 + w) * 512);
    }
    __syncthreads();
#pragma unroll
    for (int kk = 0; kk < 2; ++kk) {
      f16x8 af[2], bf[4];
#pragma unroll
      for (int m = 0; m < 2; ++m)
        af[m] = *reinterpret_cast<const f16x8*>(As + (wr + m * 16 + lr) * 64 + kk * 32 + lq * 8);
#pragma unroll
      for (int n = 0; n < 4; ++n)
        bf[n] = *reinterpret_cast<const f16x8*>(Bs + (wc + n * 16 + lr) * 64 + kk * 32 + lq * 8);
#pragma unroll
      for (int m = 0; m < 2; ++m)
#pragma unroll
        for (int n = 0; n < 4; ++n)
          acc[m][n] = __builtin_amdgcn_mfma_f32_16x16x32_f16(af[m], bf[n], acc[m][n], 0, 0, 0);
    }
    __syncthreads();
  }
#pragma unroll
  for (int m = 0; m < 2; ++m)
#pragma unroll
    for (int n = 0; n < 4; ++n)
#pragma unroll
      for (int r = 0; r < 4; ++r) {
        int row = m0 + wr + m * 16 + lq * 4 + r;
        int col = n0 + wc + n * 16 + lr;
        out[(size_t)row * N + col] = acc[m][n][r];
      }
}

// ---------------------------------------------------------------------------
// Fused flash attention (T5: scores = QK^T + bias, no 1/sqrt scale).
// v12 = v11 + IN-REGISTER P (no Ps LDS roundtrip). Key: MFMA k-index is a
// free summation label. Permute kv<->k-slot with pi(i,lq,j) =
// i*32 + (j>=4)*16 + lq*4 + (j&3), applied to BOTH PV operands:
//  - A-operand (P): slot (lq,j) of pa_i = exp(S[c=2i+(j>=4)][r=j&3]) -- the
//    values the lane ALREADY holds from swapped QK^T. Pure registers.
//  - B-operand (V^T): 4x ds_read_b64 per dh-block (two 4-elem runs at
//    kv stride 16), 2-way under the existing g^(row&7) granule swizzle.
// Removes 4 ds_write + 2 ds_read + lgkm serialization per tile; LDS 32 KB.
// ---------------------------------------------------------------------------
__global__ __launch_bounds__(256) void k_attn(const f16* __restrict__ qb,
                                              const f16* __restrict__ kb,
                                              const f16* __restrict__ vtb,
                                              const float* __restrict__ bias,
                                              f16* __restrict__ ctx) {
  const int bid = blockIdx.x;
  const int ord = (bid & 7) * 128 + (bid >> 3);  // XCD-chunked: 2 heads/XCD
  const int h = ord >> 6, qt = (ord >> 2) & 15, b = ord & 3;
  const int bh = b * 16 + h;
  const int q0 = qt * 64;
  const int tid = threadIdx.x, w = tid >> 6, l = tid & 63;
  const int lr = l & 15, lq = l >> 4;

  __shared__ f16 Kb[2][4096];  // [kv=64][dh=64], granule swz g^(row&7)
  __shared__ f16 Vb[2][4096];  // [dh=64][kv=64], granule swz g^(row&7)

  // Q B-fragment: Q[q=w*16+lr][dh=lq*8 (+32)]
  const f16* qp = qb + ((size_t)bh * 1024 + q0 + w * 16 + lr) * 64 + lq * 8;
  f16x8 qf0 = *reinterpret_cast<const f16x8*>(qp);
  f16x8 qf1 = *reinterpret_cast<const f16x8*>(qp + 32);

  f32x4 O[4] = {};
  float mrun = -3.0e38f, rsum = 0.f;  // per-lane; q-row = lr

  const f16* kbase = kb + (size_t)bh * 65536;
  const f16* vbase = vtb + (size_t)bh * 65536;
  // per-lane bias base: S[c] init needs bias[q=q0+w*16+lr][t*64+c*16+lq*4..+3]
  const float* bq = bias + ((size_t)h * 1024 + q0 + w * 16 + lr) * 1024 + lq * 4;

  // DMA staging: 512 chunks of 16B per tile; round i, wave w, lane l.
  auto stage = [&](int t, int nxt) {
#pragma unroll
    for (int i = 0; i < 2; ++i) {
      int c = (i * 4 + w) * 64 + l;
      int row = c >> 3, g = (c & 7) ^ (row & 7);
      LOADLDS16(kbase + (size_t)(t * 64 + row) * 64 + g * 8,
                &Kb[nxt][(i * 4 + w) * 512]);
      LOADLDS16(vbase + (size_t)row * 1024 + t * 64 + g * 8,
                &Vb[nxt][(i * 4 + w) * 512]);
    }
  };

  // ---- prologue: stage tile 0 ----
  stage(0, 0);
  __syncthreads();

#pragma unroll 1
  for (int t = 0; t < 16; ++t) {
    const int cur = t & 1;
    // ---- issue next tile's DMA + this tile's bias loads (pinned) ----
    if (t < 15) stage(t + 1, cur ^ 1);
    f32x4 bf[4];
#pragma unroll
    for (int c = 0; c < 4; ++c)
      bf[c] = *reinterpret_cast<const f32x4*>(bq + t * 64 + c * 16);
    __builtin_amdgcn_sched_barrier(0);

    // ---- S^T = K Q^T  (rows kv = c*16+lq*4+r, cols q = w*16+lr) ----
    f32x4 S[4] = {};
    __builtin_amdgcn_s_setprio(1);
#pragma unroll
    for (int c = 0; c < 4; ++c) {
      int row = c * 16 + lr;
      const f16* kbp = &Kb[cur][row * 64];
      f16x8 kf0 = *reinterpret_cast<const f16x8*>(kbp + ((lq ^ (row & 7)) * 8));
      f16x8 kf1 = *reinterpret_cast<const f16x8*>(kbp + (((4 + lq) ^ (row & 7)) * 8));
      S[c] = __builtin_amdgcn_mfma_f32_16x16x32_f16(kf0, qf0, S[c], 0, 0, 0);
      S[c] = __builtin_amdgcn_mfma_f32_16x16x32_f16(kf1, qf1, S[c], 0, 0, 0);
    }
    __builtin_amdgcn_s_setprio(0);

    // ---- + bias (registers) ----
#pragma unroll
    for (int c = 0; c < 4; ++c)
#pragma unroll
      for (int r = 0; r < 4; ++r) S[c][r] += bf[c][r];

    // ---- defer-max (T13): per-lane bound check; rare reduce+rescale ----
    float tmax = fmaxf(
        fmaxf(fmaxf(fmaxf(S[0][0], S[0][1]), fmaxf(S[0][2], S[0][3])),
              fmaxf(fmaxf(S[1][0], S[1][1]), fmaxf(S[1][2], S[1][3]))),
        fmaxf(fmaxf(fmaxf(S[2][0], S[2][1]), fmaxf(S[2][2], S[2][3])),
              fmaxf(fmaxf(S[3][0], S[3][1]), fmaxf(S[3][2], S[3][3]))));
    if (!__all(tmax <= mrun + 8.0f)) {
      tmax = fmaxf(tmax, __shfl_xor(tmax, 16, 64));
      tmax = fmaxf(tmax, __shfl_xor(tmax, 32, 64));
      float mnew = fmaxf(mrun, tmax);
      float sc = __expf(mrun - mnew);
      mrun = mnew;
      rsum *= sc;
      int sb = l & 48;
#pragma unroll
      for (int r = 0; r < 4; ++r) {
        float scO = __shfl(sc, sb | (lq * 4 + r), 64);
#pragma unroll
        for (int c = 0; c < 4; ++c) O[c][r] *= scO;
      }
    }

    // ---- P = exp(S - m) in REGISTERS (pi-permuted A-fragments) ----
    f32x4 p[4];
#pragma unroll
    for (int c = 0; c < 4; ++c) {
#pragma unroll
      for (int r = 0; r < 4; ++r) p[c][r] = __expf(S[c][r] - mrun);
      rsum += (p[c][0] + p[c][1]) + (p[c][2] + p[c][3]);
    }
    f16x8 pa0, pa1;
#pragma unroll
    for (int j = 0; j < 4; ++j) {
      pa0[j] = (f16)p[0][j];
      pa0[4 + j] = (f16)p[1][j];
      pa1[j] = (f16)p[2][j];
      pa1[4 + j] = (f16)p[3][j];
    }

    // ---- O += P @ V (B-side pi: 4x b64 per dh-block) ----
    __builtin_amdgcn_s_setprio(1);
#pragma unroll
    for (int c = 0; c < 4; ++c) {
      int row = c * 16 + lr;
      const f16* vbp = &Vb[cur][row * 64];
      int s8 = row & 7, sub = (lq & 1) * 4, gh = lq >> 1;
      f16x4 v0 = *reinterpret_cast<const f16x4*>(vbp + ((gh ^ s8) * 8 + sub));
      f16x4 v1 = *reinterpret_cast<const f16x4*>(vbp + (((2 + gh) ^ s8) * 8 + sub));
      f16x4 v2 = *reinterpret_cast<const f16x4*>(vbp + (((4 + gh) ^ s8) * 8 + sub));
      f16x4 v3 = *reinterpret_cast<const f16x4*>(vbp + (((6 + gh) ^ s8) * 8 + sub));
      f16x8 vf0, vf1;
#pragma unroll
      for (int j = 0; j < 4; ++j) {
        vf0[j] = v0[j];
        vf0[4 + j] = v1[j];
        vf1[j] = v2[j];
        vf1[4 + j] = v3[j];
      }
      O[c] = __builtin_amdgcn_mfma_f32_16x16x32_f16(pa0, vf0, O[c], 0, 0, 0);
      O[c] = __builtin_amdgcn_mfma_f32_16x16x32_f16(pa1, vf1, O[c], 0, 0, 0);
    }
    __builtin_amdgcn_s_setprio(0);

    __syncthreads();
  }

  // ---- deferred sum reduction across the 4 lq replicas ----
  rsum += __shfl_xor(rsum, 16, 64);
  rsum += __shfl_xor(rsum, 32, 64);
  int sb = l & 48;
  float rs[4];
#pragma unroll
  for (int r = 0; r < 4; ++r) rs[r] = __shfl(rsum, sb | (lq * 4 + r), 64);

  // ---- epilogue: ctx[b][q][h*64+dh] f16 (O: q=lq*4+r, dh=c*16+lr) ----
#pragma unroll
  for (int c = 0; c < 4; ++c)
#pragma unroll
    for (int r = 0; r < 4; ++r) {
      float o = O[c][r] / rs[r];
      int row = q0 + w * 16 + lq * 4 + r;
      ctx[((size_t)b * 1024 + row) * 1024 + h * 64 + c * 16 + lr] = (f16)o;
    }
}

// ---------------------------------------------------------------------------
extern "C" void kernel_launch(void* const* d_in, const int* in_sizes, int n_in,
                              void* d_out, int out_size, void* d_ws,
                              size_t ws_size, hipStream_t stream) {
  const float* input_ids = (const float*)d_in[0];
  const float* enc = (const float*)d_in[1];
  const float* bias = (const float*)d_in[2];
  const float* Wq = (const float*)d_in[3];
  const float* Wk = (const float*)d_in[4];
  const float* Wv = (const float*)d_in[5];
  const float* Wo = (const float*)d_in[6];

  char* ws = (char*)d_ws;
  const size_t MB = 1024 * 1024;
  f16* Xq  = (f16*)(ws + 0 * MB);   // 8 MB; dead after QKV-proj -> reused as ctx
  f16* Xkv = (f16*)(ws + 8 * MB);   // 8 MB (GEMM A input; NOT reused now)
  f16* Wqt = (f16*)(ws + 16 * MB);  // 2 MB each; Wqt|Wkt|Wvt contiguous = [3072][1024]
  f16* Wkt = (f16*)(ws + 18 * MB);
  f16* Wvt = (f16*)(ws + 20 * MB);
  f16* Wot = (f16*)(ws + 22 * MB);
  f16* qbuf = (f16*)(ws + 24 * MB); // 8 MB [bh][s][dh]; kbuf plane follows;
  f16* kbuf = (f16*)(ws + 32 * MB); // plane 2 = vtb [bh][dh][s] (transposed in epi)
  f16* vtb  = (f16*)(ws + 40 * MB);
  f16* ctxb = Xq;   // [4096][1024]

  k_cast2<<<8192, 256, 0, stream>>>(input_ids, enc, Xq, Xkv);
  k_castw_t<<<dim3(16, 16, 4), 256, 0, stream>>>(Wq, Wk, Wv, Wo, Wqt, Wkt, Wvt, Wot);

  // fused Q+K+V projection (V written transposed in epilogue)
  k_gemm_qkv<<<dim3(24, 32), 256, 0, stream>>>(Xq, Xkv, Wqt, qbuf);

  k_attn<<<1024, 256, 0, stream>>>(qbuf, kbuf, vtb, bias, ctxb);

  k_gemm_o<<<dim3(8, 64), 256, 0, stream>>>(ctxb, Wot, (float*)d_out, 4096, 1024, 1024);
}